// Round 1
// baseline (274.693 us; speedup 1.0000x reference)
//
#include <hip/hip_runtime.h>

// Guided filter, R=1, EPS=1e-6, shape (8,3,1024,1024) fp32.
// Fully fused: one kernel, halo-2 LDS tiling. Output tile 64x16 per 256-thread block.
//
// Stage 1: load x,y (TW+4)x(TH+4) tile into LDS (replication-clamped coords).
// Stage 2: compute A,b on (TW+2)x(TH+2) region. For halo positions outside the
//          image, A must equal A(clamp(pos)) -> clamp the CENTER coordinate
//          first, then sum the 3x3 neighborhood from the halo-2 tile.
// Stage 3: 3x3 box over A,b in LDS, res = mean(A)*x + mean(b), trunc, clamp.

#define TW 64
#define TH 16

__global__ __launch_bounds__(256) void gf_kernel(
    const float* __restrict__ x, const float* __restrict__ y,
    float* __restrict__ out, int H, int W) {
  const int img = blockIdx.z;
  const size_t base = (size_t)img * H * W;
  const int tx0 = blockIdx.x * TW;
  const int ty0 = blockIdx.y * TH;

  __shared__ float sx[TH + 4][TW + 4];
  __shared__ float sy[TH + 4][TW + 4];
  __shared__ float sA[TH + 2][TW + 2];
  __shared__ float sB[TH + 2][TW + 2];

  const int tid = threadIdx.y * 64 + threadIdx.x;  // blockDim = (64,4)

  // ---- Stage 1: load x,y halo-2 tile (clamped = replication pad) ----
  for (int i = tid; i < (TH + 4) * (TW + 4); i += 256) {
    int ly = i / (TW + 4);
    int lx = i - ly * (TW + 4);
    int gy = min(max(ty0 + ly - 2, 0), H - 1);
    int gx = min(max(tx0 + lx - 2, 0), W - 1);
    size_t g = base + (size_t)gy * W + gx;
    sx[ly][lx] = x[g];
    sy[ly][lx] = y[g];
  }
  __syncthreads();

  // ---- Stage 2: A,b on (TH+2)x(TW+2) ----
  const float inv9 = 1.0f / 9.0f;
  for (int i = tid; i < (TH + 2) * (TW + 2); i += 256) {
    int ly = i / (TW + 2);
    int lx = i - ly * (TW + 2);
    // global position of this A entry; clamp CENTER for replication semantics
    int cy = min(max(ty0 + ly - 1, 0), H - 1);
    int cx = min(max(tx0 + lx - 1, 0), W - 1);
    int sy0 = cy - ty0 + 2;  // LDS coords of clamped center in halo-2 tile
    int sx0 = cx - tx0 + 2;
    float Sx = 0.f, Sy = 0.f, Sxy = 0.f, Sxx = 0.f;
#pragma unroll
    for (int dy = -1; dy <= 1; ++dy)
#pragma unroll
      for (int dx = -1; dx <= 1; ++dx) {
        float vx = sx[sy0 + dy][sx0 + dx];
        float vy = sy[sy0 + dy][sx0 + dx];
        Sx += vx;
        Sy += vy;
        Sxy += vx * vy;
        Sxx += vx * vx;
      }
    float mx = Sx * inv9, my = Sy * inv9;
    float cov = Sxy * inv9 - mx * my;
    float var = Sxx * inv9 - mx * mx;
    float A = cov / (var + 1e-6f);
    sA[ly][lx] = A;
    sB[ly][lx] = my - A * mx;
  }
  __syncthreads();

  // ---- Stage 3: box(A), box(b), output ----
  for (int ry = threadIdx.y; ry < TH; ry += 4) {
    int lx = threadIdx.x;  // 0..63
    float SA = 0.f, SB = 0.f;
#pragma unroll
    for (int dy = 0; dy < 3; ++dy)
#pragma unroll
      for (int dx = 0; dx < 3; ++dx) {
        SA += sA[ry + dy][lx + dx];
        SB += sB[ry + dy][lx + dx];
      }
    float xv = sx[ry + 2][lx + 2];
    float res = SA * inv9 * xv + SB * inv9;
    float t = truncf(res);
    t = fminf(fmaxf(t, 0.0f), 255.0f);
    out[base + (size_t)(ty0 + ry) * W + (tx0 + lx)] = t;
  }
}

extern "C" void kernel_launch(void* const* d_in, const int* in_sizes, int n_in,
                              void* d_out, int out_size, void* d_ws, size_t ws_size,
                              hipStream_t stream) {
  const float* x = (const float*)d_in[0];
  const float* y = (const float*)d_in[1];
  float* out = (float*)d_out;
  const int H = 1024, W = 1024;
  const int imgs = in_sizes[0] / (H * W);  // 8*3 = 24
  dim3 block(64, 4, 1);
  dim3 grid(W / TW, H / TH, imgs);
  gf_kernel<<<grid, block, 0, stream>>>(x, y, out, H, W);
}